// Round 3
// baseline (576.962 us; speedup 1.0000x reference)
//
#include <hip/hip_runtime.h>
#include <math.h>

#define HEAD 128
typedef _Float16 f16;
typedef _Float16 f16x8 __attribute__((ext_vector_type(8)));
typedef _Float16 f16x4 __attribute__((ext_vector_type(4)));
typedef float f32x4 __attribute__((ext_vector_type(4)));

// ---------------- compile-time Möbius band table ----------------
constexpr int mu_of(int n) {
  int m = n, cnt = 0;
  for (int p = 2; p * p <= m; ++p) {
    if (m % p == 0) {
      m /= p; ++cnt;
      if (m % p == 0) return 0;
    }
  }
  if (m > 1) ++cnt;
  return (cnt & 1) ? -1 : 1;
}
constexpr int key_of(int idx) {
  int mu = mu_of(idx + 1);
  return mu == 1 ? 0 : (mu == 0 ? 1 : 2);
}
struct Tbl {
  int band[HEAD];
  float qm[HEAD];
};
constexpr Tbl make_tbl() {
  Tbl t{};
  constexpr float qv[4] = {15.f, 7.f, 7.f, 3.f};
  for (int p = 0; p < HEAD; ++p) {
    int kp = key_of(p);
    int rank = 0;
    for (int j = 0; j < HEAD; ++j) {
      int kj = key_of(j);
      if (kj < kp || (kj == kp && j < p)) ++rank;
    }
    t.band[p] = rank >> 5;
    t.qm[p] = qv[rank >> 5];
  }
  return t;
}
__constant__ Tbl g_tbl = make_tbl();

// ---------------- f32 -> (hi,lo) f16 split, pre-scaled by 64 ----------------
__global__ __launch_bounds__(256) void split64(const float* __restrict__ s,
                                               f16* __restrict__ h,
                                               f16* __restrict__ l, int n4) {
  int i = blockIdx.x * blockDim.x + threadIdx.x;
  if (i >= n4) return;
  float4 v = ((const float4*)s)[i];
  v.x *= 64.f; v.y *= 64.f; v.z *= 64.f; v.w *= 64.f;
  f16 hx = (f16)v.x, hy = (f16)v.y, hz = (f16)v.z, hw = (f16)v.w;
  f16 lx = (f16)(v.x - (float)hx);
  f16 ly = (f16)(v.y - (float)hy);
  f16 lz = (f16)(v.z - (float)hz);
  f16 lw = (f16)(v.w - (float)hw);
  f16x4 hv = {hx, hy, hz, hw};
  f16x4 lv = {lx, ly, lz, lw};
  *(f16x4*)(h + 4 * (size_t)i) = hv;
  *(f16x4*)(l + 4 * (size_t)i) = lv;
}

// ---------------- async global->LDS, 16B ----------------
// LDS operand is the WAVE-UNIFORM base; HW adds lane*16.
__device__ __forceinline__ void dma16(const f16* g, f16* l) {
  __builtin_amdgcn_global_load_lds(
      (const __attribute__((address_space(1))) unsigned int*)g,
      (__attribute__((address_space(3))) unsigned int*)l, 16, 0, 0);
}

// ---------------- MFMA GEMM: 64x128 tile, 4 waves, 2-phase dbuf ----------
// C[M,N] = (Ah+Al)(Bh+Bl)^T /4096 + bias, 3-term f16 split (AlBl dropped).
// Double-buffered LDS, ONE __syncthreads per K-step; prefetch of tile t+1
// issued right after the barrier so its drain is covered by frag-read+MFMA
// of tile t (plus co-resident blocks: 640 blocks -> 2.5 blocks/CU).
// LDS staged in MFMA-fragment order (chunk c = rows 16c..16c+15):
//   lds[c*512 + lane*8 + e] = X(row0 + c*16 + (lane&15), k0 + (lane>>4)*8 + e)
// so frag reads are ds_read_b128 at lane*16 -> zero bank conflicts.
__global__ __launch_bounds__(256) void gemm_f16split_2ph(
    const f16* __restrict__ Ah, const f16* __restrict__ Al,
    const f16* __restrict__ Bh, const f16* __restrict__ Bl,
    const float* __restrict__ bias, float* __restrict__ C,
    int M, int N, int K) {
  __shared__ f16 sAh[2][2048];  // 64 rows  x 32 K (4 chunks)
  __shared__ f16 sAl[2][2048];
  __shared__ f16 sBh[2][4096];  // 128 rows x 32 K (8 chunks)
  __shared__ f16 sBl[2][4096];

  const int tid = threadIdx.x;
  const int lane = tid & 63;
  const int wave = tid >> 6;   // 0..3
  const int wr = wave >> 1;    // 0..1 -> 32-row sub-tile
  const int wc = wave & 1;     // 0..1 -> 64-col sub-tile

  // --- XCD-aware bijective swizzle, column-major tile order:
  // chunk of nwg/8 consecutive blocks per XCD covers few N-slices x all M
  // -> per-XCD hot set = one 2.6MB B-slice (L2) + streaming A.
  const int nbm = M >> 6;   // tiles along M (16)
  const int nwg = gridDim.x;
  int wgid = blockIdx.x;
  if ((nwg & 7) == 0) {
    const int cpx = nwg >> 3;
    wgid = (wgid & 7) * cpx + (wgid >> 3);
  }
  const int mb = wgid % nbm;  // column-major: M fastest
  const int nb = wgid / nbm;
  const int m0 = mb * 64;
  const int n0 = nb * 128;

  // --- staging addressing (frag order); 6 dma16 per wave per K-step ---
  const int srow = lane & 15;
  const int ksel = (lane >> 4) * 8;
  const f16* pAh = Ah + (size_t)(m0 + wave * 16 + srow) * K + ksel;
  const f16* pAl = Al + (size_t)(m0 + wave * 16 + srow) * K + ksel;
  const f16* pBh = Bh + (size_t)(n0 + wave * 16 + srow) * K + ksel;
  const f16* pBl = Bl + (size_t)(n0 + wave * 16 + srow) * K + ksel;
  const size_t r64 = (size_t)64 * K;  // +64 rows (B chunks 4..7)

  f32x4 acc[2][4];
#pragma unroll
  for (int i = 0; i < 2; ++i)
#pragma unroll
    for (int j = 0; j < 4; ++j) acc[i][j] = (f32x4){0.f, 0.f, 0.f, 0.f};

  // stage K-tile at byte-k k0 into buffer b (24 KB total per block-step)
  auto stage = [&](int k0, int b) {
    dma16(pAh + k0, &sAh[b][wave * 512]);
    dma16(pAl + k0, &sAl[b][wave * 512]);
    dma16(pBh + k0, &sBh[b][wave * 512]);
    dma16(pBh + k0 + r64, &sBh[b][(4 + wave) * 512]);
    dma16(pBl + k0, &sBl[b][wave * 512]);
    dma16(pBl + k0 + r64, &sBl[b][(4 + wave) * 512]);
  };

  stage(0, 0);

  const int lb = lane * 8;            // lane's 16B frag slot (f16 units)
  const int aoff = (wr * 2) * 512 + lb;  // A chunks 2wr..2wr+1
  const int boff = (wc * 4) * 512 + lb;  // B chunks 4wc..4wc+3

  const int nt = K >> 5;  // 160
  int buf = 0;

  for (int t = 0; t < nt; ++t) {
    __syncthreads();  // vmcnt(0)+lgkmcnt(0)+barrier: tile t resident,
                      // all waves done reading buf^1 (prev step)

    if (t + 1 < nt) stage((t + 1) * 32, buf ^ 1);  // prefetch under compute

    f16x8 ah[2], al[2], bh[4], bl[4];
#pragma unroll
    for (int i = 0; i < 2; ++i) {
      ah[i] = *(const f16x8*)&sAh[buf][aoff + i * 512];
      al[i] = *(const f16x8*)&sAl[buf][aoff + i * 512];
    }
#pragma unroll
    for (int j = 0; j < 4; ++j) {
      bh[j] = *(const f16x8*)&sBh[buf][boff + j * 512];
      bl[j] = *(const f16x8*)&sBl[buf][boff + j * 512];
    }

#pragma unroll
    for (int i = 0; i < 2; ++i)
#pragma unroll
      for (int j = 0; j < 4; ++j) {
        acc[i][j] = __builtin_amdgcn_mfma_f32_16x16x32_f16(ah[i], bh[j], acc[i][j], 0, 0, 0);
        acc[i][j] = __builtin_amdgcn_mfma_f32_16x16x32_f16(al[i], bh[j], acc[i][j], 0, 0, 0);
        acc[i][j] = __builtin_amdgcn_mfma_f32_16x16x32_f16(ah[i], bl[j], acc[i][j], 0, 0, 0);
      }

    buf ^= 1;
  }

  // epilogue: C/D layout col=lane&15, row=(lane>>4)*4+r
  const float inv = 1.f / 4096.f;
  const int frow = lane & 15;
  const int kq = lane >> 4;
#pragma unroll
  for (int j = 0; j < 4; ++j) {
    const int col = n0 + wc * 64 + j * 16 + frow;
    const float bv = bias[col];
#pragma unroll
    for (int i = 0; i < 2; ++i) {
#pragma unroll
      for (int r = 0; r < 4; ++r) {
        const int row = m0 + wr * 32 + i * 16 + kq * 4 + r;
        C[(size_t)row * N + col] = acc[i][j][r] * inv + bv;
      }
    }
  }
}

// ---------------- fallback fp32 GEMM (proven) ----------------
#define BM 128
#define BN 64
#define BKK 8
#define TM 8
#define TN 4

__global__ __launch_bounds__(256) void sgemm_nt(
    const float* __restrict__ A, const float* __restrict__ B,
    const float* __restrict__ bias, float* __restrict__ C,
    int M, int N, int K) {
  __shared__ float As[BKK][BM];
  __shared__ float Bs[BKK][BN];

  const int tid = threadIdx.x;
  const int tn = tid & 15;
  const int tm = tid >> 4;
  const int bx = blockIdx.x;
  const int by = blockIdx.y;

  const float* Ab = A + (size_t)by * BM * K;
  const float* Bb = B + (size_t)bx * BN * K;

  const int ar = tid >> 1;
  const int ak = (tid & 1) * 4;

  float acc[TM][TN];
#pragma unroll
  for (int i = 0; i < TM; ++i)
#pragma unroll
    for (int j = 0; j < TN; ++j) acc[i][j] = 0.f;

  for (int k0 = 0; k0 < K; k0 += BKK) {
    float4 av = *(const float4*)(Ab + (size_t)ar * K + k0 + ak);
    float4 bv = make_float4(0.f, 0.f, 0.f, 0.f);
    if (tid < 128) bv = *(const float4*)(Bb + (size_t)ar * K + k0 + ak);

    __syncthreads();
    As[ak + 0][ar] = av.x;
    As[ak + 1][ar] = av.y;
    As[ak + 2][ar] = av.z;
    As[ak + 3][ar] = av.w;
    if (tid < 128) {
      Bs[ak + 0][ar] = bv.x;
      Bs[ak + 1][ar] = bv.y;
      Bs[ak + 2][ar] = bv.z;
      Bs[ak + 3][ar] = bv.w;
    }
    __syncthreads();

#pragma unroll
    for (int kk = 0; kk < BKK; ++kk) {
      float a[TM], b[TN];
#pragma unroll
      for (int i = 0; i < TM; ++i) a[i] = As[kk][tm * TM + i];
#pragma unroll
      for (int j = 0; j < TN; ++j) b[j] = Bs[kk][tn * TN + j];
#pragma unroll
      for (int i = 0; i < TM; ++i)
#pragma unroll
        for (int j = 0; j < TN; ++j) acc[i][j] += a[i] * b[j];
    }
  }

  const int row0 = by * BM + tm * TM;
  const int col0 = bx * BN + tn * TN;
  float bj[TN];
#pragma unroll
  for (int j = 0; j < TN; ++j) bj[j] = bias[col0 + j];
#pragma unroll
  for (int i = 0; i < TM; ++i) {
    float4 v = make_float4(acc[i][0] + bj[0], acc[i][1] + bj[1],
                           acc[i][2] + bj[2], acc[i][3] + bj[3]);
    *(float4*)(C + (size_t)(row0 + i) * N + col0) = v;
  }
}

// ---------------- Hadamard + banded quant-dequant + inverse ----------------
__device__ inline void fwht2(float& e0, float& e1, int lane) {
  float a = e0 + e1;
  float b = e0 - e1;
  e0 = a;
  e1 = b;
#pragma unroll
  for (int s = 1; s <= 32; s <<= 1) {
    float p0 = __shfl_xor(e0, s);
    float p1 = __shfl_xor(e1, s);
    bool up = (lane & s) != 0;
    e0 = up ? (p0 - e0) : (e0 + p0);
    e1 = up ? (p1 - e1) : (e1 + p1);
  }
}

__global__ __launch_bounds__(256) void hadq(const float* __restrict__ Y,
                                            float* __restrict__ O, int nrows) {
  const int lane = threadIdx.x & 63;
  const int wave = (blockIdx.x * (blockDim.x >> 6)) + (threadIdx.x >> 6);
  const int nwaves = gridDim.x * (blockDim.x >> 6);

  const int b0 = g_tbl.band[lane];
  const int b1 = g_tbl.band[lane + 64];
  const float qm0 = g_tbl.qm[lane];
  const float qm1 = g_tbl.qm[lane + 64];

  for (int row = wave; row < nrows; row += nwaves) {
    const float* y = Y + (size_t)row * HEAD;
    float e0 = y[lane];
    float e1 = y[lane + 64];

    fwht2(e0, e1, lane);

    float f0 = fabsf(e0), f1 = fabsf(e1);
    float ab0 = fmaxf(b0 == 0 ? f0 : 0.f, b1 == 0 ? f1 : 0.f);
    float ab1 = fmaxf(b0 == 1 ? f0 : 0.f, b1 == 1 ? f1 : 0.f);
    float ab2 = fmaxf(b0 == 2 ? f0 : 0.f, b1 == 2 ? f1 : 0.f);
    float ab3 = fmaxf(b0 == 3 ? f0 : 0.f, b1 == 3 ? f1 : 0.f);
#pragma unroll
    for (int s = 32; s >= 1; s >>= 1) {
      ab0 = fmaxf(ab0, __shfl_xor(ab0, s));
      ab1 = fmaxf(ab1, __shfl_xor(ab1, s));
      ab2 = fmaxf(ab2, __shfl_xor(ab2, s));
      ab3 = fmaxf(ab3, __shfl_xor(ab3, s));
    }
    float am0 = b0 == 0 ? ab0 : (b0 == 1 ? ab1 : (b0 == 2 ? ab2 : ab3));
    float am1 = b1 == 0 ? ab0 : (b1 == 1 ? ab1 : (b1 == 2 ? ab2 : ab3));

    float s0 = am0 > 0.f ? am0 / qm0 : 1.0f;
    float s1 = am1 > 0.f ? am1 / qm1 : 1.0f;

    float q0 = fminf(fmaxf(rintf(e0 / s0), -qm0), qm0);
    float q1 = fminf(fmaxf(rintf(e1 / s1), -qm1), qm1);
    e0 = q0 * s0;
    e1 = q1 * s1;

    fwht2(e0, e1, lane);
    float r0 = e0 * 0.0078125f;
    float r1 = e1 * 0.0078125f;
    if (r0 != r0) r0 = 0.f;
    if (r1 != r1) r1 = 0.f;
    r0 = fminf(fmaxf(r0, -65504.f), 65504.f);
    r1 = fminf(fmaxf(r1, -65504.f), 65504.f);

    float* o = O + (size_t)row * HEAD;
    o[lane] = r0;
    o[lane + 64] = r1;
  }
}

// ---------------- launch ----------------
extern "C" void kernel_launch(void* const* d_in, const int* in_sizes, int n_in,
                              void* d_out, int out_size, void* d_ws, size_t ws_size,
                              hipStream_t stream) {
  const float* x = (const float*)d_in[0];
  const float* W = (const float*)d_in[1];
  const float* b = (const float*)d_in[2];
  float* out = (float*)d_out;

  const int N = in_sizes[2];      // 5120
  const int K = N;                // 5120
  const int M = in_sizes[0] / K;  // 1024

  const size_t MK = (size_t)M * K;
  const size_t NK = (size_t)N * K;
  const size_t need = (MK + NK) * 2 * sizeof(f16);  // hi+lo for x and W

  if (ws_size >= need && (M % 64) == 0 && (N % 128) == 0 && (K % 32) == 0) {
    f16* xh = (f16*)d_ws;
    f16* xl = xh + MK;
    f16* wh = xl + MK;
    f16* wl = wh + NK;

    const int n4x = (int)(MK / 4);
    const int n4w = (int)(NK / 4);
    split64<<<(n4x + 255) / 256, 256, 0, stream>>>(x, xh, xl, n4x);
    split64<<<(n4w + 255) / 256, 256, 0, stream>>>(W, wh, wl, n4w);

    const int nwg = (M / 64) * (N / 128);  // 640
    gemm_f16split_2ph<<<nwg, 256, 0, stream>>>(xh, xl, wh, wl, b, out, M, N, K);
  } else {
    dim3 grid(N / BN, M / BM);
    sgemm_nt<<<grid, 256, 0, stream>>>(x, W, b, out, M, N, K);
  }

  const int nrows = out_size / HEAD;
  hadq<<<512, 256, 0, stream>>>(out, out, nrows);
}

// Round 4
// 419.771 us; speedup vs baseline: 1.3745x; 1.3745x over previous
//
#include <hip/hip_runtime.h>
#include <math.h>

#define HEAD 128
typedef _Float16 f16;
typedef _Float16 f16x8 __attribute__((ext_vector_type(8)));
typedef _Float16 f16x4 __attribute__((ext_vector_type(4)));
typedef float f32x4 __attribute__((ext_vector_type(4)));

// ---------------- compile-time Möbius band table ----------------
constexpr int mu_of(int n) {
  int m = n, cnt = 0;
  for (int p = 2; p * p <= m; ++p) {
    if (m % p == 0) {
      m /= p; ++cnt;
      if (m % p == 0) return 0;
    }
  }
  if (m > 1) ++cnt;
  return (cnt & 1) ? -1 : 1;
}
constexpr int key_of(int idx) {
  int mu = mu_of(idx + 1);
  return mu == 1 ? 0 : (mu == 0 ? 1 : 2);
}
struct Tbl {
  int band[HEAD];
  float qm[HEAD];
};
constexpr Tbl make_tbl() {
  Tbl t{};
  constexpr float qv[4] = {15.f, 7.f, 7.f, 3.f};
  for (int p = 0; p < HEAD; ++p) {
    int kp = key_of(p);
    int rank = 0;
    for (int j = 0; j < HEAD; ++j) {
      int kj = key_of(j);
      if (kj < kp || (kj == kp && j < p)) ++rank;
    }
    t.band[p] = rank >> 5;
    t.qm[p] = qv[rank >> 5];
  }
  return t;
}
__constant__ Tbl g_tbl = make_tbl();

// -------- fused f32 -> (hi,lo) f16 split for x and W, pre-scaled by 64 -----
__global__ __launch_bounds__(256) void split64_2(
    const float* __restrict__ x, const float* __restrict__ W,
    f16* __restrict__ xh, f16* __restrict__ xl,
    f16* __restrict__ wh, f16* __restrict__ wl, int n4x, int n4tot) {
  int i = blockIdx.x * blockDim.x + threadIdx.x;
  if (i >= n4tot) return;
  const float* s;
  f16 *h, *l;
  int j;
  if (i < n4x) {
    s = x; h = xh; l = xl; j = i;
  } else {
    s = W; h = wh; l = wl; j = i - n4x;
  }
  float4 v = ((const float4*)s)[j];
  v.x *= 64.f; v.y *= 64.f; v.z *= 64.f; v.w *= 64.f;
  f16 hx = (f16)v.x, hy = (f16)v.y, hz = (f16)v.z, hw = (f16)v.w;
  f16 lx = (f16)(v.x - (float)hx);
  f16 ly = (f16)(v.y - (float)hy);
  f16 lz = (f16)(v.z - (float)hz);
  f16 lw = (f16)(v.w - (float)hw);
  f16x4 hv = {hx, hy, hz, hw};
  f16x4 lv = {lx, ly, lz, lw};
  *(f16x4*)(h + 4 * (size_t)j) = hv;
  *(f16x4*)(l + 4 * (size_t)j) = lv;
}

// ---------------- async global->LDS, 16B ----------------
// LDS operand is the WAVE-UNIFORM base; HW adds lane*16.
__device__ __forceinline__ void dma16(const f16* g, f16* l) {
  __builtin_amdgcn_global_load_lds(
      (const __attribute__((address_space(1))) unsigned int*)g,
      (__attribute__((address_space(3))) unsigned int*)l, 16, 0, 0);
}

// ---------------- MFMA GEMM, split-K (m97 structure) ---------------------
// 128x128 tile, 4 waves, single-buffered LDS, 2 __syncthreads per K-step,
// prefetch under MFMA. Grid = tiles * nsplit; split s covers K-range
// [s*K/nsplit, (s+1)*K/nsplit). Split 0 writes C0 (+bias); split s>0 writes
// partial buffer Cp[(s-1)*M*N] (no bias). hadq sums the partials.
// LDS staged in MFMA-fragment order (chunk c = rows 16c..16c+15):
//   lds[c*512 + lane*8 + e] = X(row0 + c*16 + (lane&15), k0 + (lane>>4)*8 + e)
// so frag reads are ds_read_b128 at lane*16 -> zero bank conflicts.
__global__ __launch_bounds__(256) void gemm_f16split_sk(
    const f16* __restrict__ Ah, const f16* __restrict__ Al,
    const f16* __restrict__ Bh, const f16* __restrict__ Bl,
    const float* __restrict__ bias, float* __restrict__ C0,
    float* __restrict__ Cp, int M, int N, int K, int nsplit) {
  __shared__ f16 sAh[4096];
  __shared__ f16 sAl[4096];
  __shared__ f16 sBh[4096];
  __shared__ f16 sBl[4096];

  const int tid = threadIdx.x;
  const int lane = tid & 63;
  const int wave = tid >> 6;   // 0..3
  const int wr = wave >> 1;    // wave row (0..1) -> 64-row sub-tile
  const int wc = wave & 1;     // wave col (0..1) -> 64-col sub-tile

  // --- XCD-aware bijective swizzle ---
  const int nbm = M >> 7;            // 128-tiles along M (8)
  const int nbn = N >> 7;            // 128-tiles along N (40)
  const int tiles = nbm * nbn;       // 320
  const int nwg = gridDim.x;         // tiles * nsplit
  int wgid = blockIdx.x;
  if ((nwg & 7) == 0) {
    const int cpx = nwg >> 3;
    wgid = (wgid & 7) * cpx + (wgid >> 3);
  }
  const int split = wgid / tiles;
  const int tix = wgid % tiles;
  const int mb = tix % nbm;          // column-major: M fastest (B reuse)
  const int nb = tix / nbm;
  const int m0 = mb * 128;
  const int n0 = nb * 128;
  const int Ks = K / nsplit;
  const int k_beg = split * Ks;
  const int k_end = k_beg + Ks;

  // --- staging addressing (frag order) ---
  const int rsel = wave * 16 + (lane & 15);
  const int ksel = (lane >> 4) * 8;
  const f16* pAh = Ah + (size_t)(m0 + rsel) * K + ksel;
  const f16* pAl = Al + (size_t)(m0 + rsel) * K + ksel;
  const f16* pBh = Bh + (size_t)(n0 + rsel) * K + ksel;
  const f16* pBl = Bl + (size_t)(n0 + rsel) * K + ksel;
  const size_t r64 = (size_t)64 * K;  // +64 rows

  f16* dA0h = sAh + wave * 512;         // chunk 'wave'
  f16* dA1h = sAh + 2048 + wave * 512;  // chunk 4+wave
  f16* dA0l = sAl + wave * 512;
  f16* dA1l = sAl + 2048 + wave * 512;
  f16* dB0h = sBh + wave * 512;
  f16* dB1h = sBh + 2048 + wave * 512;
  f16* dB0l = sBl + wave * 512;
  f16* dB1l = sBl + 2048 + wave * 512;

  f32x4 acc[4][4];
#pragma unroll
  for (int i = 0; i < 4; ++i)
#pragma unroll
    for (int j = 0; j < 4; ++j) acc[i][j] = (f32x4){0.f, 0.f, 0.f, 0.f};

  auto stage = [&](int k0) {
    dma16(pAh + k0, dA0h);
    dma16(pAh + k0 + r64, dA1h);
    dma16(pAl + k0, dA0l);
    dma16(pAl + k0 + r64, dA1l);
    dma16(pBh + k0, dB0h);
    dma16(pBh + k0 + r64, dB1h);
    dma16(pBl + k0, dB0l);
    dma16(pBl + k0 + r64, dB1l);
  };

  stage(k_beg);

  const int lb = lane * 8;          // lane's 16B frag slot (f16 units)
  const int ca = wr * 4 * 512;      // A chunk base for this wave
  const int cb = wc * 4 * 512;      // B chunk base for this wave

  for (int k0 = k_beg; k0 < k_end; k0 += 32) {
    __syncthreads();  // vmcnt(0)+barrier: tile resident for all waves

    f16x8 ah[4], al[4], bh[4], bl[4];
#pragma unroll
    for (int i = 0; i < 4; ++i) {
      ah[i] = *(const f16x8*)&sAh[ca + i * 512 + lb];
      al[i] = *(const f16x8*)&sAl[ca + i * 512 + lb];
      bh[i] = *(const f16x8*)&sBh[cb + i * 512 + lb];
      bl[i] = *(const f16x8*)&sBl[cb + i * 512 + lb];
    }
    __syncthreads();  // all frags in regs; LDS safe to overwrite

    if (k0 + 32 < k_end) stage(k0 + 32);  // prefetch hides under MFMA phase

#pragma unroll
    for (int i = 0; i < 4; ++i)
#pragma unroll
      for (int j = 0; j < 4; ++j) {
        acc[i][j] = __builtin_amdgcn_mfma_f32_16x16x32_f16(ah[i], bh[j], acc[i][j], 0, 0, 0);
        acc[i][j] = __builtin_amdgcn_mfma_f32_16x16x32_f16(al[i], bh[j], acc[i][j], 0, 0, 0);
        acc[i][j] = __builtin_amdgcn_mfma_f32_16x16x32_f16(ah[i], bl[j], acc[i][j], 0, 0, 0);
      }
  }

  // epilogue: C/D layout col=lane&15, row=(lane>>4)*4+r
  const float inv = 1.f / 4096.f;
  const int frow = lane & 15;
  const int kq = lane >> 4;
  const size_t MN = (size_t)M * N;
  float* dst = (split == 0) ? C0 : (Cp + (size_t)(split - 1) * MN);
#pragma unroll
  for (int j = 0; j < 4; ++j) {
    const int col = n0 + wc * 64 + j * 16 + frow;
    const float bv = (split == 0) ? bias[col] : 0.f;
#pragma unroll
    for (int i = 0; i < 4; ++i) {
#pragma unroll
      for (int r = 0; r < 4; ++r) {
        const int row = m0 + wr * 64 + i * 16 + kq * 4 + r;
        dst[(size_t)row * N + col] = acc[i][j][r] * inv + bv;
      }
    }
  }
}

// ---------------- fallback fp32 GEMM (proven) ----------------
#define BM 128
#define BN 64
#define BKK 8
#define TM 8
#define TN 4

__global__ __launch_bounds__(256) void sgemm_nt(
    const float* __restrict__ A, const float* __restrict__ B,
    const float* __restrict__ bias, float* __restrict__ C,
    int M, int N, int K) {
  __shared__ float As[BKK][BM];
  __shared__ float Bs[BKK][BN];

  const int tid = threadIdx.x;
  const int tn = tid & 15;
  const int tm = tid >> 4;
  const int bx = blockIdx.x;
  const int by = blockIdx.y;

  const float* Ab = A + (size_t)by * BM * K;
  const float* Bb = B + (size_t)bx * BN * K;

  const int ar = tid >> 1;
  const int ak = (tid & 1) * 4;

  float acc[TM][TN];
#pragma unroll
  for (int i = 0; i < TM; ++i)
#pragma unroll
    for (int j = 0; j < TN; ++j) acc[i][j] = 0.f;

  for (int k0 = 0; k0 < K; k0 += BKK) {
    float4 av = *(const float4*)(Ab + (size_t)ar * K + k0 + ak);
    float4 bv = make_float4(0.f, 0.f, 0.f, 0.f);
    if (tid < 128) bv = *(const float4*)(Bb + (size_t)ar * K + k0 + ak);

    __syncthreads();
    As[ak + 0][ar] = av.x;
    As[ak + 1][ar] = av.y;
    As[ak + 2][ar] = av.z;
    As[ak + 3][ar] = av.w;
    if (tid < 128) {
      Bs[ak + 0][ar] = bv.x;
      Bs[ak + 1][ar] = bv.y;
      Bs[ak + 2][ar] = bv.z;
      Bs[ak + 3][ar] = bv.w;
    }
    __syncthreads();

#pragma unroll
    for (int kk = 0; kk < BKK; ++kk) {
      float a[TM], b[TN];
#pragma unroll
      for (int i = 0; i < TM; ++i) a[i] = As[kk][tm * TM + i];
#pragma unroll
      for (int j = 0; j < TN; ++j) b[j] = Bs[kk][tn * TN + j];
#pragma unroll
      for (int i = 0; i < TM; ++i)
#pragma unroll
        for (int j = 0; j < TN; ++j) acc[i][j] += a[i] * b[j];
    }
  }

  const int row0 = by * BM + tm * TM;
  const int col0 = bx * BN + tn * TN;
  float bj[TN];
#pragma unroll
  for (int j = 0; j < TN; ++j) bj[j] = bias[col0 + j];
#pragma unroll
  for (int i = 0; i < TM; ++i) {
    float4 v = make_float4(acc[i][0] + bj[0], acc[i][1] + bj[1],
                           acc[i][2] + bj[2], acc[i][3] + bj[3]);
    *(float4*)(C + (size_t)(row0 + i) * N + col0) = v;
  }
}

// ---------------- Hadamard + banded quant-dequant + inverse ----------------
// Sums npart split-K partial buffers into y before the FWHT.
__device__ inline void fwht2(float& e0, float& e1, int lane) {
  float a = e0 + e1;
  float b = e0 - e1;
  e0 = a;
  e1 = b;
#pragma unroll
  for (int s = 1; s <= 32; s <<= 1) {
    float p0 = __shfl_xor(e0, s);
    float p1 = __shfl_xor(e1, s);
    bool up = (lane & s) != 0;
    e0 = up ? (p0 - e0) : (e0 + p0);
    e1 = up ? (p1 - e1) : (e1 + p1);
  }
}

__global__ __launch_bounds__(256) void hadq(const float* __restrict__ Y,
                                            const float* __restrict__ P,
                                            int npart, float* __restrict__ O,
                                            int nrows) {
  const int lane = threadIdx.x & 63;
  const int wave = (blockIdx.x * (blockDim.x >> 6)) + (threadIdx.x >> 6);
  const int nwaves = gridDim.x * (blockDim.x >> 6);

  const int b0 = g_tbl.band[lane];
  const int b1 = g_tbl.band[lane + 64];
  const float qm0 = g_tbl.qm[lane];
  const float qm1 = g_tbl.qm[lane + 64];
  const size_t MN = (size_t)nrows * HEAD;

  for (int row = wave; row < nrows; row += nwaves) {
    const float* y = Y + (size_t)row * HEAD;
    float e0 = y[lane];
    float e1 = y[lane + 64];
    for (int p = 0; p < npart; ++p) {
      const float* pp = P + (size_t)p * MN + (size_t)row * HEAD;
      e0 += pp[lane];
      e1 += pp[lane + 64];
    }

    fwht2(e0, e1, lane);

    float f0 = fabsf(e0), f1 = fabsf(e1);
    float ab0 = fmaxf(b0 == 0 ? f0 : 0.f, b1 == 0 ? f1 : 0.f);
    float ab1 = fmaxf(b0 == 1 ? f0 : 0.f, b1 == 1 ? f1 : 0.f);
    float ab2 = fmaxf(b0 == 2 ? f0 : 0.f, b1 == 2 ? f1 : 0.f);
    float ab3 = fmaxf(b0 == 3 ? f0 : 0.f, b1 == 3 ? f1 : 0.f);
#pragma unroll
    for (int s = 32; s >= 1; s >>= 1) {
      ab0 = fmaxf(ab0, __shfl_xor(ab0, s));
      ab1 = fmaxf(ab1, __shfl_xor(ab1, s));
      ab2 = fmaxf(ab2, __shfl_xor(ab2, s));
      ab3 = fmaxf(ab3, __shfl_xor(ab3, s));
    }
    float am0 = b0 == 0 ? ab0 : (b0 == 1 ? ab1 : (b0 == 2 ? ab2 : ab3));
    float am1 = b1 == 0 ? ab0 : (b1 == 1 ? ab1 : (b1 == 2 ? ab2 : ab3));

    float s0 = am0 > 0.f ? am0 / qm0 : 1.0f;
    float s1 = am1 > 0.f ? am1 / qm1 : 1.0f;

    float q0 = fminf(fmaxf(rintf(e0 / s0), -qm0), qm0);
    float q1 = fminf(fmaxf(rintf(e1 / s1), -qm1), qm1);
    e0 = q0 * s0;
    e1 = q1 * s1;

    fwht2(e0, e1, lane);
    float r0 = e0 * 0.0078125f;
    float r1 = e1 * 0.0078125f;
    if (r0 != r0) r0 = 0.f;
    if (r1 != r1) r1 = 0.f;
    r0 = fminf(fmaxf(r0, -65504.f), 65504.f);
    r1 = fminf(fmaxf(r1, -65504.f), 65504.f);

    float* o = O + (size_t)row * HEAD;
    o[lane] = r0;
    o[lane + 64] = r1;
  }
}

// ---------------- launch ----------------
extern "C" void kernel_launch(void* const* d_in, const int* in_sizes, int n_in,
                              void* d_out, int out_size, void* d_ws, size_t ws_size,
                              hipStream_t stream) {
  const float* x = (const float*)d_in[0];
  const float* W = (const float*)d_in[1];
  const float* b = (const float*)d_in[2];
  float* out = (float*)d_out;

  const int N = in_sizes[2];      // 5120
  const int K = N;                // 5120
  const int M = in_sizes[0] / K;  // 1024

  const size_t MK = (size_t)M * K;
  const size_t NK = (size_t)N * K;
  const size_t MN = (size_t)M * N;
  const size_t need = (MK + NK) * 2 * sizeof(f16);  // hi+lo for x and W

  const int nrows = out_size / HEAD;

  if (ws_size >= need && (M % 128) == 0 && (N % 128) == 0 && (K % 32) == 0) {
    f16* xh = (f16*)d_ws;
    f16* xl = xh + MK;
    f16* wh = xl + MK;
    f16* wl = wh + NK;
    float* Cp = (float*)((char*)d_ws + need);  // split-K partials

    // pick largest split-K the workspace allows (grid = 320*nsplit blocks)
    int nsplit = 1;
    if (ws_size >= need + 3 * MN * sizeof(float) && (K % 128) == 0)
      nsplit = 4;
    else if (ws_size >= need + 1 * MN * sizeof(float) && (K % 64) == 0)
      nsplit = 2;

    const int n4x = (int)(MK / 4);
    const int n4tot = (int)((MK + NK) / 4);
    split64_2<<<(n4tot + 255) / 256, 256, 0, stream>>>(x, W, xh, xl, wh, wl,
                                                       n4x, n4tot);

    const int nwg = (M / 128) * (N / 128) * nsplit;  // 320 * nsplit
    gemm_f16split_sk<<<nwg, 256, 0, stream>>>(xh, xl, wh, wl, b, out, Cp, M,
                                              N, K, nsplit);

    hadq<<<512, 256, 0, stream>>>(out, Cp, nsplit - 1, out, nrows);
  } else {
    dim3 grid(N / BN, M / BM);
    sgemm_nt<<<grid, 256, 0, stream>>>(x, W, b, out, M, N, K);
    hadq<<<512, 256, 0, stream>>>(out, (const float*)out, 0, out, nrows);
  }
}